// Round 10
// baseline (184.875 us; speedup 1.0000x reference)
//
#include <hip/hip_runtime.h>

typedef unsigned short u16;
typedef unsigned int u32;
typedef __bf16 bf16x8 __attribute__((ext_vector_type(8)));
typedef float f32x4 __attribute__((ext_vector_type(4)));
typedef u16 u16x8 __attribute__((ext_vector_type(8)));
typedef u16 u16x4 __attribute__((ext_vector_type(4)));
typedef u32 u32x2 __attribute__((ext_vector_type(2)));
typedef u32 u32x4 __attribute__((ext_vector_type(4)));

__device__ __forceinline__ u16 to_bf16(float f) {
  unsigned int u = __builtin_bit_cast(unsigned int, f);
  u += 0x7fffu + ((u >> 16) & 1u);
  return (u16)(u >> 16);
}

__device__ __forceinline__ f32x4 mfma16(bf16x8 a, bf16x8 b, f32x4 c) {
  return __builtin_amdgcn_mfma_f32_16x16x32_bf16(a, b, c, 0, 0, 0);
}

// packed f32x2 -> bf16x2 (RNE); lo16 = a, hi16 = b  (numerics verified r1/r7/r9)
__device__ __forceinline__ u32 cvtpk(float a, float b) {
  u32 r; asm("v_cvt_pk_bf16_f32 %0, %1, %2" : "=v"(r) : "v"(a), "v"(b)); return r;
}

// async global->LDS, 16B per lane; LDS dest = wave-uniform base + lane*16
#define GLD16(gp, lp) __builtin_amdgcn_global_load_lds( \
    (const __attribute__((address_space(1))) unsigned int*)(gp), \
    (__attribute__((address_space(3))) unsigned int*)(lp), 16, 0, 0)

#define WAITVM(N) asm volatile("s_waitcnt vmcnt(" #N ")" ::: "memory")
#define BARRIER() asm volatile("s_barrier" ::: "memory")

// ---------------- fp32 -> bf16 conversion of x, w_qkv, w_dense ----------------
__global__ __launch_bounds__(256) void cvt_all(
    const float* __restrict__ x, const float* __restrict__ wq, const float* __restrict__ wd,
    u16* __restrict__ xb, u16* __restrict__ wqb, u16* __restrict__ wdb) {
  long i = ((long)blockIdx.x * 256 + threadIdx.x) * 4;
  const float* s; u16* d;
  if (i < 4194304)      { s = x  + i;             d = xb  + i; }
  else if (i < 7340032) { s = wq + (i - 4194304); d = wqb + (i - 4194304); }
  else                  { s = wd + (i - 7340032); d = wdb + (i - 7340032); }
  f32x4 f = *(const f32x4*)s;
  u16x4 o;
  o[0] = to_bf16(f[0]); o[1] = to_bf16(f[1]); o[2] = to_bf16(f[2]); o[3] = to_bf16(f[3]);
  *(u16x4*)d = o;
}

// ---------------- QKV GEMM 128x128, dbuf K-loop + fused V transpose -----------
// cols <1024: Q (scaled); 1024..2047: K; >=2048: V -> vt[bh][d][kv] transposed.
__global__ __launch_bounds__(256) void gemm_qkv(const u16* __restrict__ A,
    const u16* __restrict__ Bt, u16* __restrict__ qk, u16* __restrict__ vt,
    int K, float qscale) {
  __shared__ __align__(16) u16 As[2][4096];
  __shared__ __align__(16) u16 Bs[2][4096];
  const int tid = threadIdx.x;
  const int lane = tid & 63, wave = tid >> 6;
  const int wm = (wave & 1) * 64, wn = (wave >> 1) * 64;
  const int bm = blockIdx.y * 128, bn = blockIdx.x * 128;
  const int fm = lane & 15, fk8 = (lane >> 4) * 8;
  f32x4 acc[4][4] = {};

  const int r0 = tid >> 2, c0 = (tid & 3) * 8;
  const u16* Ag = A + (long)(bm + r0) * K + c0;
  const u16* Bg = Bt + (long)(bn + r0) * K + c0;
  const long rowStep = (long)64 * K;

#define GSTAGE(K0, IB) do { \
    GLD16(Ag + (K0),           &As[IB][tid * 8]); \
    GLD16(Ag + rowStep + (K0), &As[IB][tid * 8 + 2048]); \
    GLD16(Bg + (K0),           &Bs[IB][tid * 8]); \
    GLD16(Bg + rowStep + (K0), &Bs[IB][tid * 8 + 2048]); \
  } while (0)

  GSTAGE(0, 0);
  int ib = 0;
  for (int k0 = 0; k0 < K; k0 += 32) {
    if (k0 + 32 < K) { GSTAGE(k0 + 32, ib ^ 1); WAITVM(4); }
    else             { WAITVM(0); }
    BARRIER();
    bf16x8 a[4], b[4];
#pragma unroll
    for (int i = 0; i < 4; i++) a[i] = *(const bf16x8*)&As[ib][(wm + i * 16 + fm) * 32 + fk8];
#pragma unroll
    for (int j = 0; j < 4; j++) b[j] = *(const bf16x8*)&Bs[ib][(wn + j * 16 + fm) * 32 + fk8];
#pragma unroll
    for (int i = 0; i < 4; i++)
#pragma unroll
      for (int j = 0; j < 4; j++)
        acc[i][j] = mfma16(a[i], b[j], acc[i][j]);
    BARRIER();  // all reads of As[ib]/Bs[ib] done before next GSTAGE targets it
    ib ^= 1;
  }
#undef GSTAGE

  const int er = (lane >> 4) * 4, ec = lane & 15;
  if (bn >= 2048) {
    // V region: transposed store. rows -> kv (consecutive over r), col -> (h,d)
#pragma unroll
    for (int i = 0; i < 4; i++) {
      const long row0 = bm + wm + i * 16 + er;
      const long bb = row0 >> 11;
      const int kv = (int)(row0 & 2047);
#pragma unroll
      for (int j = 0; j < 4; j++) {
        const int dcol = bn + wn + j * 16 + ec - 2048;
        u16x4 pk;
#pragma unroll
        for (int r = 0; r < 4; r++) pk[r] = to_bf16(acc[i][j][r]);
        *(u16x4*)&vt[((bb * 16 + (dcol >> 6)) * 64 + (dcol & 63)) * 2048 + kv] = pk;
      }
    }
  } else {
    const float sc = (bn < 1024) ? qscale : 1.0f;  // block-uniform
#pragma unroll
    for (int i = 0; i < 4; i++)
#pragma unroll
      for (int j = 0; j < 4; j++)
#pragma unroll
        for (int r = 0; r < 4; r++) {
          long row = bm + wm + i * 16 + er + r;
          long col = bn + wn + j * 16 + ec;
          qk[row * 2048 + col] = to_bf16(acc[i][j][r] * sc);
        }
  }
}

// ---------------- bf16 GEMM 128x64 (f32 out), dbuf K-loop ---------------------
__global__ __launch_bounds__(256) void gemm_bt_n64(const u16* __restrict__ A,
    const u16* __restrict__ Bt, float* __restrict__ C, int M, int N, int K) {
  __shared__ __align__(16) u16 As[2][4096];
  __shared__ __align__(16) u16 Bs[2][2048];
  const int tid = threadIdx.x;
  const int lane = tid & 63, wave = tid >> 6;
  const int wm = (wave & 1) * 64, wn = (wave >> 1) * 32;
  const int bm = blockIdx.y * 128, bn = blockIdx.x * 64;
  const int fm = lane & 15, fk8 = (lane >> 4) * 8;
  f32x4 acc[4][2] = {};

  const int r0 = tid >> 2, c0 = (tid & 3) * 8;
  const u16* Ag = A + (long)(bm + r0) * K + c0;
  const u16* Bg = Bt + (long)(bn + r0) * K + c0;
  const long rowStep = (long)64 * K;

#define GSTAGE(K0, IB) do { \
    GLD16(Ag + (K0),           &As[IB][tid * 8]); \
    GLD16(Ag + rowStep + (K0), &As[IB][tid * 8 + 2048]); \
    GLD16(Bg + (K0),           &Bs[IB][tid * 8]); \
  } while (0)

  GSTAGE(0, 0);
  int ib = 0;
  for (int k0 = 0; k0 < K; k0 += 32) {
    if (k0 + 32 < K) { GSTAGE(k0 + 32, ib ^ 1); WAITVM(3); }
    else             { WAITVM(0); }
    BARRIER();
    bf16x8 a[4], b[2];
#pragma unroll
    for (int i = 0; i < 4; i++) a[i] = *(const bf16x8*)&As[ib][(wm + i * 16 + fm) * 32 + fk8];
#pragma unroll
    for (int j = 0; j < 2; j++) b[j] = *(const bf16x8*)&Bs[ib][(wn + j * 16 + fm) * 32 + fk8];
#pragma unroll
    for (int i = 0; i < 4; i++)
#pragma unroll
      for (int j = 0; j < 2; j++)
        acc[i][j] = mfma16(a[i], b[j], acc[i][j]);
    BARRIER();
    ib ^= 1;
  }
#undef GSTAGE

  const int er = (lane >> 4) * 4, ec = lane & 15;
#pragma unroll
  for (int i = 0; i < 4; i++)
#pragma unroll
    for (int j = 0; j < 2; j++)
#pragma unroll
      for (int r = 0; r < 4; r++)
        C[(long)(bm + wm + i * 16 + er + r) * N + bn + wn + j * 16 + ec] = acc[i][j][r];
}

// ---------------- flash attention: register-P, K=32-perm PV, 4 blocks/CU ------
// Merge of the two verified passing structures:
//   r8: 64 q/block (16 q/wave), grid 1024 = 4 blocks/CU = 4 waves/SIMD
//   r9: K=32 PV via k-permutation (A: concat cvtpk of slices jj=2p,2p+1;
//       B: the two verified b64 V-reads glued into one bf16x8)
// Rationale (r8+r9 counters): r8 was issue-saturated (87%) with 56 MFMA/tile;
// r9 cut to 36 but had only 2 waves/SIMD. This version: 18 MFMA/tile/wave AND
// 4 waves/SIMD -- both the issue-width and the TLP lever engaged.
__global__ __launch_bounds__(256, 4) void attn_kernel(const u16* __restrict__ qk,
                                                      const u16* __restrict__ vt,
                                                      u16* __restrict__ ctx) {
  __shared__ __align__(16) u16 Kb[2][4096];  // K[kv][d], chunk c at c^(kv&7)
  __shared__ __align__(16) u16 Vb[2][4096];  // V^T[d][kv], chunk c at c^(d&7)
  const int tid = threadIdx.x, lane = tid & 63, wave = tid >> 6;
  const int fm = lane & 15, g = lane >> 4, f7 = fm & 7;

  // XCD swizzle: 32 q-tile blocks of one (b,h) share id%8 (4 bh-groups/XCD)
  const int id = blockIdx.x;               // 0..1023
  const int c = id & 7, m = id >> 3;
  const int qt = m & 31, bh = (m >> 5) * 8 + c;
  const int b = bh >> 4, h = bh & 15;
  const long tokBase = (long)b * 2048;
  const int q0 = qt * 64;

  // staging maps: wave w stages rows w*16..w*16+15 (2 ops of 8 rows each)
  const int sr8 = lane >> 3;
  const int gch = (lane & 7) ^ sr8;
  const u16* Kg = qk + (tokBase + wave * 16 + sr8) * 2048 + 1024 + h * 64 + gch * 8;
  const u16* Vg = vt + ((long)bh * 64 + wave * 16 + sr8) * 2048 + gch * 8;
  u16* KL = &Kb[0][wave * 16 * 64] + lane * 8;
  u16* VL = &Vb[0][wave * 16 * 64] + lane * 8;

#define STAGE(S0, IB) do { \
    GLD16(Kg + (long)(S0) * 2048,          KL + (IB) * 4096); \
    GLD16(Kg + (long)((S0) + 8) * 2048,    KL + (IB) * 4096 + 512); \
    GLD16(Vg + (S0),                       VL + (IB) * 4096); \
    GLD16(Vg + (S0) + (long)8 * 2048,      VL + (IB) * 4096 + 512); \
  } while (0)

  STAGE(0, 0);

  // Q B-frags (rows q0 + wave*16 + fm); pre-scaled by qscale in gemm_qkv
  bf16x8 qa0, qa1;
  {
    const long qoff = (tokBase + q0 + wave * 16 + fm) * 2048 + h * 64;
    qa0 = *(const bf16x8*)&qk[qoff + g * 8];
    qa1 = *(const bf16x8*)&qk[qoff + 32 + g * 8];
  }

  f32x4 o[4] = {};
  f32x4 ol = {};
  u16x8 onesu = {0x3F80, 0x3F80, 0x3F80, 0x3F80, 0x3F80, 0x3F80, 0x3F80, 0x3F80};
  bf16x8 ones = __builtin_bit_cast(bf16x8, onesu);

  int ib = 0;
  for (int s0 = 0; s0 < 2048; s0 += 64) {
    if (s0 + 64 < 2048) { STAGE(s0 + 64, ib ^ 1); WAITVM(4); }
    else                { WAITVM(0); }
    BARRIER();

    const u16* Kt = &Kb[ib][0];
    const u16* Vtile = &Vb[ib][0];

    // per 32-kv pair p (slices jj=2p, 2p+1): QK -> exp2/pack -> K=32 PV
#pragma unroll
    for (int p = 0; p < 2; p++) {
      u32x4 pk;  // 4 u32 = bf16x8 A-frag (k-slot 8g+i holds permuted kv)
#pragma unroll
      for (int jh = 0; jh < 2; jh++) {
        const int jj = 2 * p + jh;
        bf16x8 k0 = *(const bf16x8*)&Kt[(jj * 16 + fm) * 64 + ((g    ) ^ f7) * 8];
        bf16x8 k1 = *(const bf16x8*)&Kt[(jj * 16 + fm) * 64 + ((4 + g) ^ f7) * 8];
        f32x4 s = {};
        s = mfma16(k0, qa0, s);
        s = mfma16(k1, qa1, s);
        pk[2 * jh + 0] = cvtpk(__builtin_amdgcn_exp2f(s[0]), __builtin_amdgcn_exp2f(s[1]));
        pk[2 * jh + 1] = cvtpk(__builtin_amdgcn_exp2f(s[2]), __builtin_amdgcn_exp2f(s[3]));
      }
      // V B-frags: verified b64 addresses for jj=2p (lo) and jj=2p+1 (hi)
      bf16x8 vb[4];
#pragma unroll
      for (int jd = 0; jd < 4; jd++) {
        const int rowb = (jd * 16 + fm) * 64;
        u32x2 lo = *(const u32x2*)&Vtile[rowb + ((2 * (2 * p)     + (g >> 1)) ^ f7) * 8 + (g & 1) * 4];
        u32x2 hi = *(const u32x2*)&Vtile[rowb + ((2 * (2 * p + 1) + (g >> 1)) ^ f7) * 8 + (g & 1) * 4];
        u32x4 v4; v4[0] = lo[0]; v4[1] = lo[1]; v4[2] = hi[0]; v4[3] = hi[1];
        vb[jd] = __builtin_bit_cast(bf16x8, v4);
      }

      const bf16x8 pa = __builtin_bit_cast(bf16x8, pk);
      __builtin_amdgcn_s_setprio(1);
#pragma unroll
      for (int jd = 0; jd < 4; jd++)
        o[jd] = mfma16(pa, vb[jd], o[jd]);
      ol = mfma16(pa, ones, ol);
      __builtin_amdgcn_s_setprio(0);
    }
    BARRIER();  // LDS reads consumed; next STAGE may overwrite
    ib ^= 1;
  }
#undef STAGE

  // ctx[token][h*64+d] = O / l  (l already in the right lane: row 4g+r)
#pragma unroll
  for (int r = 0; r < 4; r++) {
    float inv = 1.0f / ol[r];
    const long obase = (tokBase + q0 + wave * 16 + g * 4 + r) * 1024 + h * 64;
#pragma unroll
    for (int jd = 0; jd < 4; jd++)
      ctx[obase + jd * 16 + fm] = to_bf16(o[jd][r] * inv);
  }
}

// ---------------- launch ------------------------------------------------------
extern "C" void kernel_launch(void* const* d_in, const int* in_sizes, int n_in,
                              void* d_out, int out_size, void* d_ws, size_t ws_size,
                              hipStream_t stream) {
  const float* x  = (const float*)d_in[0];
  const float* wq = (const float*)d_in[1];
  const float* wd = (const float*)d_in[2];
  float* out = (float*)d_out;
  char* ws = (char*)d_ws;
  // ws layout (48 MiB total)
  u16* xb   = (u16*)(ws);                          //  8 MiB  x bf16 [4096,1024]
  u16* wqb  = (u16*)(ws + 8388608);                //  6 MiB  w_qkv bf16 [3072,1024]
  u16* wdb  = (u16*)(ws + 14680064);               //  2 MiB  w_dense bf16 [1024,1024]
  u16* qkb  = (u16*)(ws + 16777216);               // 16 MiB  q|k bf16 [4096,2048]
  u16* vtb  = (u16*)(ws + 33554432);               //  8 MiB  Vt bf16 [32,64,2048]
  u16* ctxb = (u16*)(ws + 41943040);               //  8 MiB  ctx bf16 [4096,1024]

  const float sscale = 0.125f * 1.44269504f;       // 1/sqrt(64) * log2(e)

  cvt_all<<<8192, 256, 0, stream>>>(x, wq, wd, xb, wqb, wdb);
  gemm_qkv<<<dim3(24, 32), 256, 0, stream>>>(xb, wqb, qkb, vtb, 1024, sscale);
  attn_kernel<<<1024, 256, 0, stream>>>(qkb, vtb, ctxb);
  gemm_bt_n64<<<dim3(16, 32), 256, 0, stream>>>(ctxb, wdb, out, 4096, 1024, 1024);
}

// Round 11
// 171.639 us; speedup vs baseline: 1.0771x; 1.0771x over previous
//
#include <hip/hip_runtime.h>

typedef unsigned short u16;
typedef unsigned int u32;
typedef __bf16 bf16x8 __attribute__((ext_vector_type(8)));
typedef float f32x4 __attribute__((ext_vector_type(4)));
typedef u16 u16x8 __attribute__((ext_vector_type(8)));
typedef u16 u16x4 __attribute__((ext_vector_type(4)));
typedef u32 u32x2 __attribute__((ext_vector_type(2)));
typedef u32 u32x4 __attribute__((ext_vector_type(4)));

__device__ __forceinline__ u16 to_bf16(float f) {
  unsigned int u = __builtin_bit_cast(unsigned int, f);
  u += 0x7fffu + ((u >> 16) & 1u);
  return (u16)(u >> 16);
}

__device__ __forceinline__ f32x4 mfma16(bf16x8 a, bf16x8 b, f32x4 c) {
  return __builtin_amdgcn_mfma_f32_16x16x32_bf16(a, b, c, 0, 0, 0);
}

// packed f32x2 -> bf16x2 (RNE); lo16 = a, hi16 = b  (numerics verified r1/r7/r9)
__device__ __forceinline__ u32 cvtpk(float a, float b) {
  u32 r; asm("v_cvt_pk_bf16_f32 %0, %1, %2" : "=v"(r) : "v"(a), "v"(b)); return r;
}

// async global->LDS, 16B per lane; LDS dest = wave-uniform base + lane*16
#define GLD16(gp, lp) __builtin_amdgcn_global_load_lds( \
    (const __attribute__((address_space(1))) unsigned int*)(gp), \
    (__attribute__((address_space(3))) unsigned int*)(lp), 16, 0, 0)

#define WAITVM(N) asm volatile("s_waitcnt vmcnt(" #N ")" ::: "memory")
#define BARRIER() asm volatile("s_barrier" ::: "memory")

// ---------------- fp32 -> bf16 conversion of x, w_qkv, w_dense ----------------
__global__ __launch_bounds__(256) void cvt_all(
    const float* __restrict__ x, const float* __restrict__ wq, const float* __restrict__ wd,
    u16* __restrict__ xb, u16* __restrict__ wqb, u16* __restrict__ wdb) {
  long i = ((long)blockIdx.x * 256 + threadIdx.x) * 4;
  const float* s; u16* d;
  if (i < 4194304)      { s = x  + i;             d = xb  + i; }
  else if (i < 7340032) { s = wq + (i - 4194304); d = wqb + (i - 4194304); }
  else                  { s = wd + (i - 7340032); d = wdb + (i - 7340032); }
  f32x4 f = *(const f32x4*)s;
  u16x4 o;
  o[0] = to_bf16(f[0]); o[1] = to_bf16(f[1]); o[2] = to_bf16(f[2]); o[3] = to_bf16(f[3]);
  *(u16x4*)d = o;
}

// ---------------- QKV GEMM 128x128, dbuf K-loop + fused V transpose -----------
// cols <1024: Q (scaled); 1024..2047: K; >=2048: V -> vt[bh][d][kvperm].
// kvperm: within each 32-kv group, quad j -> ((j&3)<<1)|(j>>2)  (bijective).
// This makes each 16B chunk of a vt row hold kv {32p+4j..+3, 32p+16+4j..+3} --
// exactly the K=32-perm PV B-frag, so attn reads V with single b128s.
__global__ __launch_bounds__(256) void gemm_qkv(const u16* __restrict__ A,
    const u16* __restrict__ Bt, u16* __restrict__ qk, u16* __restrict__ vt,
    int K, float qscale) {
  __shared__ __align__(16) u16 As[2][4096];
  __shared__ __align__(16) u16 Bs[2][4096];
  const int tid = threadIdx.x;
  const int lane = tid & 63, wave = tid >> 6;
  const int wm = (wave & 1) * 64, wn = (wave >> 1) * 64;
  const int bm = blockIdx.y * 128, bn = blockIdx.x * 128;
  const int fm = lane & 15, fk8 = (lane >> 4) * 8;
  f32x4 acc[4][4] = {};

  const int r0 = tid >> 2, c0 = (tid & 3) * 8;
  const u16* Ag = A + (long)(bm + r0) * K + c0;
  const u16* Bg = Bt + (long)(bn + r0) * K + c0;
  const long rowStep = (long)64 * K;

#define GSTAGE(K0, IB) do { \
    GLD16(Ag + (K0),           &As[IB][tid * 8]); \
    GLD16(Ag + rowStep + (K0), &As[IB][tid * 8 + 2048]); \
    GLD16(Bg + (K0),           &Bs[IB][tid * 8]); \
    GLD16(Bg + rowStep + (K0), &Bs[IB][tid * 8 + 2048]); \
  } while (0)

  GSTAGE(0, 0);
  int ib = 0;
  for (int k0 = 0; k0 < K; k0 += 32) {
    if (k0 + 32 < K) { GSTAGE(k0 + 32, ib ^ 1); WAITVM(4); }
    else             { WAITVM(0); }
    BARRIER();
    bf16x8 a[4], b[4];
#pragma unroll
    for (int i = 0; i < 4; i++) a[i] = *(const bf16x8*)&As[ib][(wm + i * 16 + fm) * 32 + fk8];
#pragma unroll
    for (int j = 0; j < 4; j++) b[j] = *(const bf16x8*)&Bs[ib][(wn + j * 16 + fm) * 32 + fk8];
#pragma unroll
    for (int i = 0; i < 4; i++)
#pragma unroll
      for (int j = 0; j < 4; j++)
        acc[i][j] = mfma16(a[i], b[j], acc[i][j]);
    BARRIER();  // all reads of As[ib]/Bs[ib] done before next GSTAGE targets it
    ib ^= 1;
  }
#undef GSTAGE

  const int er = (lane >> 4) * 4, ec = lane & 15;
  if (bn >= 2048) {
    // V region: transposed store with quad-level kv permutation.
#pragma unroll
    for (int i = 0; i < 4; i++) {
      const long row0 = bm + wm + i * 16 + er;
      const long bb = row0 >> 11;
      const int kv = (int)(row0 & 2047);          // quad-aligned (er multiple of 4)
      const int j4 = (kv >> 2) & 7;               // quad within 32-kv group
      const int outj = ((j4 & 3) << 1) | (j4 >> 2);
      const int newkv = (kv & ~31) | (outj << 2); // permuted quad position
#pragma unroll
      for (int j = 0; j < 4; j++) {
        const int dcol = bn + wn + j * 16 + ec - 2048;
        u16x4 pk;
#pragma unroll
        for (int r = 0; r < 4; r++) pk[r] = to_bf16(acc[i][j][r]);
        *(u16x4*)&vt[((bb * 16 + (dcol >> 6)) * 64 + (dcol & 63)) * 2048 + newkv] = pk;
      }
    }
  } else {
    const float sc = (bn < 1024) ? qscale : 1.0f;  // block-uniform
#pragma unroll
    for (int i = 0; i < 4; i++)
#pragma unroll
      for (int j = 0; j < 4; j++)
#pragma unroll
        for (int r = 0; r < 4; r++) {
          long row = bm + wm + i * 16 + er + r;
          long col = bn + wn + j * 16 + ec;
          qk[row * 2048 + col] = to_bf16(acc[i][j][r] * sc);
        }
  }
}

// ---------------- bf16 GEMM 128x64 (f32 out), dbuf K-loop ---------------------
__global__ __launch_bounds__(256) void gemm_bt_n64(const u16* __restrict__ A,
    const u16* __restrict__ Bt, float* __restrict__ C, int M, int N, int K) {
  __shared__ __align__(16) u16 As[2][4096];
  __shared__ __align__(16) u16 Bs[2][2048];
  const int tid = threadIdx.x;
  const int lane = tid & 63, wave = tid >> 6;
  const int wm = (wave & 1) * 64, wn = (wave >> 1) * 32;
  const int bm = blockIdx.y * 128, bn = blockIdx.x * 64;
  const int fm = lane & 15, fk8 = (lane >> 4) * 8;
  f32x4 acc[4][2] = {};

  const int r0 = tid >> 2, c0 = (tid & 3) * 8;
  const u16* Ag = A + (long)(bm + r0) * K + c0;
  const u16* Bg = Bt + (long)(bn + r0) * K + c0;
  const long rowStep = (long)64 * K;

#define GSTAGE(K0, IB) do { \
    GLD16(Ag + (K0),           &As[IB][tid * 8]); \
    GLD16(Ag + rowStep + (K0), &As[IB][tid * 8 + 2048]); \
    GLD16(Bg + (K0),           &Bs[IB][tid * 8]); \
  } while (0)

  GSTAGE(0, 0);
  int ib = 0;
  for (int k0 = 0; k0 < K; k0 += 32) {
    if (k0 + 32 < K) { GSTAGE(k0 + 32, ib ^ 1); WAITVM(3); }
    else             { WAITVM(0); }
    BARRIER();
    bf16x8 a[4], b[2];
#pragma unroll
    for (int i = 0; i < 4; i++) a[i] = *(const bf16x8*)&As[ib][(wm + i * 16 + fm) * 32 + fk8];
#pragma unroll
    for (int j = 0; j < 2; j++) b[j] = *(const bf16x8*)&Bs[ib][(wn + j * 16 + fm) * 32 + fk8];
#pragma unroll
    for (int i = 0; i < 4; i++)
#pragma unroll
      for (int j = 0; j < 2; j++)
        acc[i][j] = mfma16(a[i], b[j], acc[i][j]);
    BARRIER();
    ib ^= 1;
  }
#undef GSTAGE

  const int er = (lane >> 4) * 4, ec = lane & 15;
#pragma unroll
  for (int i = 0; i < 4; i++)
#pragma unroll
    for (int j = 0; j < 2; j++)
#pragma unroll
      for (int r = 0; r < 4; r++)
        C[(long)(bm + wm + i * 16 + er + r) * N + bn + wn + j * 16 + ec] = acc[i][j][r];
}

// ---------------- flash attention: register-P, K=32-perm PV, b128 V-reads -----
// r9-verified structure (4 waves x 32 q, 512 blocks). Single delta: vt's global
// kv layout is quad-permuted (see gemm_qkv), so each PV B-frag is ONE b128 read
// at chunk (4p+g)^f7 -- same address form as the verified r0 V-read. DS reads
// per wave/tile: 24 -> 16 (all b128); glue VALU eliminated.
__global__ __launch_bounds__(256, 2) void attn_kernel(const u16* __restrict__ qk,
                                                      const u16* __restrict__ vt,
                                                      u16* __restrict__ ctx) {
  __shared__ __align__(16) u16 Kb[2][4096];  // K[kv][d], chunk c at c^(kv&7)
  __shared__ __align__(16) u16 Vb[2][4096];  // V^T[d][kvperm], chunk c at c^(d&7)
  const int tid = threadIdx.x, lane = tid & 63, wave = tid >> 6;
  const int fm = lane & 15, g = lane >> 4, f7 = fm & 7;

  // XCD swizzle: 16 q-tile blocks of one (b,h) share id%8
  const int id = blockIdx.x;               // 0..511
  const int c = id & 7, m = id >> 3;
  const int qt = m & 15, bh = (m >> 4) * 8 + c;
  const int b = bh >> 4, h = bh & 15;
  const long tokBase = (long)b * 2048;
  const int q0 = qt * 128;

  // staging maps: wave w stages rows w*16..w*16+15 (2 ops of 8 rows each)
  const int sr8 = lane >> 3;
  const int gch = (lane & 7) ^ sr8;
  const u16* Kg = qk + (tokBase + wave * 16 + sr8) * 2048 + 1024 + h * 64 + gch * 8;
  const u16* Vg = vt + ((long)bh * 64 + wave * 16 + sr8) * 2048 + gch * 8;
  u16* KL = &Kb[0][wave * 16 * 64] + lane * 8;
  u16* VL = &Vb[0][wave * 16 * 64] + lane * 8;

#define STAGE(S0, IB) do { \
    GLD16(Kg + (long)(S0) * 2048,          KL + (IB) * 4096); \
    GLD16(Kg + (long)((S0) + 8) * 2048,    KL + (IB) * 4096 + 512); \
    GLD16(Vg + (S0),                       VL + (IB) * 4096); \
    GLD16(Vg + (S0) + (long)8 * 2048,      VL + (IB) * 4096 + 512); \
  } while (0)

  STAGE(0, 0);

  // Q B-frags for 2 sub-tiles (rows q0 + wave*32 + t*16 + fm); pre-scaled
  bf16x8 qa[2][2];
#pragma unroll
  for (int t = 0; t < 2; t++) {
    const long qoff = (tokBase + q0 + wave * 32 + t * 16 + fm) * 2048 + h * 64;
    qa[t][0] = *(const bf16x8*)&qk[qoff + g * 8];
    qa[t][1] = *(const bf16x8*)&qk[qoff + 32 + g * 8];
  }

  f32x4 o[2][4] = {};
  f32x4 ol[2] = {};
  u16x8 onesu = {0x3F80, 0x3F80, 0x3F80, 0x3F80, 0x3F80, 0x3F80, 0x3F80, 0x3F80};
  bf16x8 ones = __builtin_bit_cast(bf16x8, onesu);

  int ib = 0;
  for (int s0 = 0; s0 < 2048; s0 += 64) {
    if (s0 + 64 < 2048) { STAGE(s0 + 64, ib ^ 1); WAITVM(4); }
    else                { WAITVM(0); }
    BARRIER();

    const u16* Kt = &Kb[ib][0];
    const u16* Vtile = &Vb[ib][0];

    // per 32-kv pair p (slices jj=2p, 2p+1): QK -> exp2/pack -> K=32 PV
#pragma unroll
    for (int p = 0; p < 2; p++) {
      u32x4 pk[2];  // [t]: 4 u32 = bf16x8 A-frag (k-slot 8g+i <- kv perm)
#pragma unroll
      for (int jh = 0; jh < 2; jh++) {
        const int jj = 2 * p + jh;
        bf16x8 k0 = *(const bf16x8*)&Kt[(jj * 16 + fm) * 64 + ((g    ) ^ f7) * 8];
        bf16x8 k1 = *(const bf16x8*)&Kt[(jj * 16 + fm) * 64 + ((4 + g) ^ f7) * 8];
#pragma unroll
        for (int t = 0; t < 2; t++) {
          f32x4 s = {};
          s = mfma16(k0, qa[t][0], s);
          s = mfma16(k1, qa[t][1], s);
          pk[t][2 * jh + 0] = cvtpk(__builtin_amdgcn_exp2f(s[0]), __builtin_amdgcn_exp2f(s[1]));
          pk[t][2 * jh + 1] = cvtpk(__builtin_amdgcn_exp2f(s[2]), __builtin_amdgcn_exp2f(s[3]));
        }
      }
      // V B-frags: single b128 per jd -- permuted chunk (4p+g), XOR-swizzled
      bf16x8 vb[4];
#pragma unroll
      for (int jd = 0; jd < 4; jd++)
        vb[jd] = *(const bf16x8*)&Vtile[(jd * 16 + fm) * 64 + ((4 * p + g) ^ f7) * 8];

      __builtin_amdgcn_s_setprio(1);
#pragma unroll
      for (int t = 0; t < 2; t++) {
        bf16x8 pa = __builtin_bit_cast(bf16x8, pk[t]);
#pragma unroll
        for (int jd = 0; jd < 4; jd++)
          o[t][jd] = mfma16(pa, vb[jd], o[t][jd]);
        ol[t] = mfma16(pa, ones, ol[t]);
      }
      __builtin_amdgcn_s_setprio(0);
    }
    BARRIER();  // LDS reads consumed; next STAGE may overwrite
    ib ^= 1;
  }
#undef STAGE

  // ctx[token][h*64+d] = O / l  (l already in the right lane: row 4g+r)
#pragma unroll
  for (int t = 0; t < 2; t++) {
#pragma unroll
    for (int r = 0; r < 4; r++) {
      float inv = 1.0f / ol[t][r];
      const long obase = (tokBase + q0 + wave * 32 + t * 16 + g * 4 + r) * 1024 + h * 64;
#pragma unroll
      for (int jd = 0; jd < 4; jd++)
        ctx[obase + jd * 16 + fm] = to_bf16(o[t][jd][r] * inv);
    }
  }
}

// ---------------- launch ------------------------------------------------------
extern "C" void kernel_launch(void* const* d_in, const int* in_sizes, int n_in,
                              void* d_out, int out_size, void* d_ws, size_t ws_size,
                              hipStream_t stream) {
  const float* x  = (const float*)d_in[0];
  const float* wq = (const float*)d_in[1];
  const float* wd = (const float*)d_in[2];
  float* out = (float*)d_out;
  char* ws = (char*)d_ws;
  // ws layout (48 MiB total)
  u16* xb   = (u16*)(ws);                          //  8 MiB  x bf16 [4096,1024]
  u16* wqb  = (u16*)(ws + 8388608);                //  6 MiB  w_qkv bf16 [3072,1024]
  u16* wdb  = (u16*)(ws + 14680064);               //  2 MiB  w_dense bf16 [1024,1024]
  u16* qkb  = (u16*)(ws + 16777216);               // 16 MiB  q|k bf16 [4096,2048]
  u16* vtb  = (u16*)(ws + 33554432);               //  8 MiB  Vt bf16 [32,64,2048] (kv quad-permuted)
  u16* ctxb = (u16*)(ws + 41943040);               //  8 MiB  ctx bf16 [4096,1024]

  const float sscale = 0.125f * 1.44269504f;       // 1/sqrt(64) * log2(e)

  cvt_all<<<8192, 256, 0, stream>>>(x, wq, wd, xb, wqb, wdb);
  gemm_qkv<<<dim3(24, 32), 256, 0, stream>>>(xb, wqb, qkb, vtb, 1024, sscale);
  attn_kernel<<<512, 256, 0, stream>>>(qkb, vtb, ctxb);
  gemm_bt_n64<<<dim3(16, 32), 256, 0, stream>>>(ctxb, wdb, out, 4096, 1024, 1024);
}

// Round 12
// 168.378 us; speedup vs baseline: 1.0980x; 1.0194x over previous
//
#include <hip/hip_runtime.h>

typedef unsigned short u16;
typedef unsigned int u32;
typedef __bf16 bf16x8 __attribute__((ext_vector_type(8)));
typedef float f32x4 __attribute__((ext_vector_type(4)));
typedef u16 u16x8 __attribute__((ext_vector_type(8)));
typedef u16 u16x4 __attribute__((ext_vector_type(4)));
typedef u32 u32x2 __attribute__((ext_vector_type(2)));
typedef u32 u32x4 __attribute__((ext_vector_type(4)));

__device__ __forceinline__ u16 to_bf16(float f) {
  unsigned int u = __builtin_bit_cast(unsigned int, f);
  u += 0x7fffu + ((u >> 16) & 1u);
  return (u16)(u >> 16);
}

__device__ __forceinline__ f32x4 mfma16(bf16x8 a, bf16x8 b, f32x4 c) {
  return __builtin_amdgcn_mfma_f32_16x16x32_bf16(a, b, c, 0, 0, 0);
}

// packed f32x2 -> bf16x2 (RNE); lo16 = a, hi16 = b  (numerics verified r1/r7/r9)
__device__ __forceinline__ u32 cvtpk(float a, float b) {
  u32 r; asm("v_cvt_pk_bf16_f32 %0, %1, %2" : "=v"(r) : "v"(a), "v"(b)); return r;
}

// async global->LDS, 16B per lane; LDS dest = wave-uniform base + lane*16
#define GLD16(gp, lp) __builtin_amdgcn_global_load_lds( \
    (const __attribute__((address_space(1))) unsigned int*)(gp), \
    (__attribute__((address_space(3))) unsigned int*)(lp), 16, 0, 0)

#define WAITVM(N) asm volatile("s_waitcnt vmcnt(" #N ")" ::: "memory")
#define BARRIER() asm volatile("s_barrier" ::: "memory")

// ---------------- fp32 -> bf16 conversion of x, w_qkv, w_dense ----------------
__global__ __launch_bounds__(256) void cvt_all(
    const float* __restrict__ x, const float* __restrict__ wq, const float* __restrict__ wd,
    u16* __restrict__ xb, u16* __restrict__ wqb, u16* __restrict__ wdb) {
  long i = ((long)blockIdx.x * 256 + threadIdx.x) * 4;
  const float* s; u16* d;
  if (i < 4194304)      { s = x  + i;             d = xb  + i; }
  else if (i < 7340032) { s = wq + (i - 4194304); d = wqb + (i - 4194304); }
  else                  { s = wd + (i - 7340032); d = wdb + (i - 7340032); }
  f32x4 f = *(const f32x4*)s;
  u16x4 o;
  o[0] = to_bf16(f[0]); o[1] = to_bf16(f[1]); o[2] = to_bf16(f[2]); o[3] = to_bf16(f[3]);
  *(u16x4*)d = o;
}

// ---------------- QKV GEMM 128x128, dbuf K-loop + fused V transpose -----------
// cols <1024: Q (scaled); 1024..2047: K; >=2048: V -> vt[bh][d][kvperm].
// kvperm: within each 32-kv group, quad j -> ((j&3)<<1)|(j>>2)  (bijective).
__global__ __launch_bounds__(256) void gemm_qkv(const u16* __restrict__ A,
    const u16* __restrict__ Bt, u16* __restrict__ qk, u16* __restrict__ vt,
    int K, float qscale) {
  __shared__ __align__(16) u16 As[2][4096];
  __shared__ __align__(16) u16 Bs[2][4096];
  const int tid = threadIdx.x;
  const int lane = tid & 63, wave = tid >> 6;
  const int wm = (wave & 1) * 64, wn = (wave >> 1) * 64;
  const int bm = blockIdx.y * 128, bn = blockIdx.x * 128;
  const int fm = lane & 15, fk8 = (lane >> 4) * 8;
  f32x4 acc[4][4] = {};

  const int r0 = tid >> 2, c0 = (tid & 3) * 8;
  const u16* Ag = A + (long)(bm + r0) * K + c0;
  const u16* Bg = Bt + (long)(bn + r0) * K + c0;
  const long rowStep = (long)64 * K;

#define GSTAGE(K0, IB) do { \
    GLD16(Ag + (K0),           &As[IB][tid * 8]); \
    GLD16(Ag + rowStep + (K0), &As[IB][tid * 8 + 2048]); \
    GLD16(Bg + (K0),           &Bs[IB][tid * 8]); \
    GLD16(Bg + rowStep + (K0), &Bs[IB][tid * 8 + 2048]); \
  } while (0)

  GSTAGE(0, 0);
  int ib = 0;
  for (int k0 = 0; k0 < K; k0 += 32) {
    if (k0 + 32 < K) { GSTAGE(k0 + 32, ib ^ 1); WAITVM(4); }
    else             { WAITVM(0); }
    BARRIER();
    bf16x8 a[4], b[4];
#pragma unroll
    for (int i = 0; i < 4; i++) a[i] = *(const bf16x8*)&As[ib][(wm + i * 16 + fm) * 32 + fk8];
#pragma unroll
    for (int j = 0; j < 4; j++) b[j] = *(const bf16x8*)&Bs[ib][(wn + j * 16 + fm) * 32 + fk8];
#pragma unroll
    for (int i = 0; i < 4; i++)
#pragma unroll
      for (int j = 0; j < 4; j++)
        acc[i][j] = mfma16(a[i], b[j], acc[i][j]);
    BARRIER();  // all reads of As[ib]/Bs[ib] done before next GSTAGE targets it
    ib ^= 1;
  }
#undef GSTAGE

  const int er = (lane >> 4) * 4, ec = lane & 15;
  if (bn >= 2048) {
    // V region: transposed store with quad-level kv permutation.
#pragma unroll
    for (int i = 0; i < 4; i++) {
      const long row0 = bm + wm + i * 16 + er;
      const long bb = row0 >> 11;
      const int kv = (int)(row0 & 2047);          // quad-aligned (er multiple of 4)
      const int j4 = (kv >> 2) & 7;               // quad within 32-kv group
      const int outj = ((j4 & 3) << 1) | (j4 >> 2);
      const int newkv = (kv & ~31) | (outj << 2); // permuted quad position
#pragma unroll
      for (int j = 0; j < 4; j++) {
        const int dcol = bn + wn + j * 16 + ec - 2048;
        u16x4 pk;
#pragma unroll
        for (int r = 0; r < 4; r++) pk[r] = to_bf16(acc[i][j][r]);
        *(u16x4*)&vt[((bb * 16 + (dcol >> 6)) * 64 + (dcol & 63)) * 2048 + newkv] = pk;
      }
    }
  } else {
    const float sc = (bn < 1024) ? qscale : 1.0f;  // block-uniform
#pragma unroll
    for (int i = 0; i < 4; i++)
#pragma unroll
      for (int j = 0; j < 4; j++)
#pragma unroll
        for (int r = 0; r < 4; r++) {
          long row = bm + wm + i * 16 + er + r;
          long col = bn + wn + j * 16 + ec;
          qk[row * 2048 + col] = to_bf16(acc[i][j][r] * sc);
        }
  }
}

// ---------------- bf16 GEMM 128x64 (f32 out), BK=64 + XOR-swizzled LDS --------
// Rebuilt (r12): BK 32->64 halves barrier count (32->16 pairs), 16 MFMA + 12
// b128 ds_reads per phase. LDS chunk-swizzle (attn-verified gch pattern): LDS
// slot s of row r holds global k-chunk s^(r&7); staging pre-swizzles the global
// source, reads XOR by (fm&7) -- the XORs cancel so every lane gets the true
// k-chunk g (A/B k-alignment preserved); banks spread across all 32 (2-way max).
// LDS 48KB (2x(16K A + 8K B)) -> 3 blocks/CU capacity; grid 512 = 2/CU.
__global__ __launch_bounds__(256) void gemm_bt_n64(const u16* __restrict__ A,
    const u16* __restrict__ Bt, float* __restrict__ C, int M, int N, int K) {
  __shared__ __align__(16) u16 As[2][8192];  // 128 x 64, chunk-swizzled rows
  __shared__ __align__(16) u16 Bs[2][4096];  //  64 x 64, chunk-swizzled rows
  const int tid = threadIdx.x;
  const int lane = tid & 63, wave = tid >> 6;
  const int wm = (wave & 1) * 64, wn = (wave >> 1) * 32;
  const int bm = blockIdx.y * 128, bn = blockIdx.x * 64;
  const int fm = lane & 15, g = lane >> 4, f7 = fm & 7;
  f32x4 acc[4][2] = {};

  // staging map: thread tid -> row r0 = tid>>3 (32 rows/op), dest chunk tid&7;
  // global source chunk = (tid&7) ^ (r0&7)  (involution; cancels on read)
  const int r0 = tid >> 3;
  const int gchunk = (tid & 7) ^ (r0 & 7);
  const u16* Ag = A + (long)(bm + r0) * K + gchunk * 8;
  const u16* Bg = Bt + (long)(bn + r0) * K + gchunk * 8;
  const long rowStep32 = (long)32 * K;

#define GSTAGE(K0, IB) do { \
    GLD16(Ag + (K0),                   &As[IB][tid * 8]); \
    GLD16(Ag + rowStep32 + (K0),       &As[IB][tid * 8 + 2048]); \
    GLD16(Ag + 2 * rowStep32 + (K0),   &As[IB][tid * 8 + 4096]); \
    GLD16(Ag + 3 * rowStep32 + (K0),   &As[IB][tid * 8 + 6144]); \
    GLD16(Bg + (K0),                   &Bs[IB][tid * 8]); \
    GLD16(Bg + rowStep32 + (K0),       &Bs[IB][tid * 8 + 2048]); \
  } while (0)

  GSTAGE(0, 0);
  int ib = 0;
  for (int k0 = 0; k0 < K; k0 += 64) {
    if (k0 + 64 < K) { GSTAGE(k0 + 64, ib ^ 1); WAITVM(6); }
    else             { WAITVM(0); }
    BARRIER();
#pragma unroll
    for (int kk = 0; kk < 2; kk++) {
      bf16x8 a[4], b[2];
#pragma unroll
      for (int i = 0; i < 4; i++)
        a[i] = *(const bf16x8*)&As[ib][(wm + i * 16 + fm) * 64 + ((kk * 4 + g) ^ f7) * 8];
#pragma unroll
      for (int j = 0; j < 2; j++)
        b[j] = *(const bf16x8*)&Bs[ib][(wn + j * 16 + fm) * 64 + ((kk * 4 + g) ^ f7) * 8];
#pragma unroll
      for (int i = 0; i < 4; i++)
#pragma unroll
        for (int j = 0; j < 2; j++)
          acc[i][j] = mfma16(a[i], b[j], acc[i][j]);
    }
    BARRIER();
    ib ^= 1;
  }
#undef GSTAGE

  const int er = (lane >> 4) * 4, ec = lane & 15;
#pragma unroll
  for (int i = 0; i < 4; i++)
#pragma unroll
    for (int j = 0; j < 2; j++)
#pragma unroll
      for (int r = 0; r < 4; r++)
        C[(long)(bm + wm + i * 16 + er + r) * N + bn + wn + j * 16 + ec] = acc[i][j][r];
}

// ---------------- flash attention: register-P, K=32-perm PV, b128 V-reads -----
// r11-verified (45.1 us, 0 bank conflicts). Unchanged.
__global__ __launch_bounds__(256, 2) void attn_kernel(const u16* __restrict__ qk,
                                                      const u16* __restrict__ vt,
                                                      u16* __restrict__ ctx) {
  __shared__ __align__(16) u16 Kb[2][4096];  // K[kv][d], chunk c at c^(kv&7)
  __shared__ __align__(16) u16 Vb[2][4096];  // V^T[d][kvperm], chunk c at c^(d&7)
  const int tid = threadIdx.x, lane = tid & 63, wave = tid >> 6;
  const int fm = lane & 15, g = lane >> 4, f7 = fm & 7;

  // XCD swizzle: 16 q-tile blocks of one (b,h) share id%8
  const int id = blockIdx.x;               // 0..511
  const int c = id & 7, m = id >> 3;
  const int qt = m & 15, bh = (m >> 4) * 8 + c;
  const int b = bh >> 4, h = bh & 15;
  const long tokBase = (long)b * 2048;
  const int q0 = qt * 128;

  // staging maps: wave w stages rows w*16..w*16+15 (2 ops of 8 rows each)
  const int sr8 = lane >> 3;
  const int gch = (lane & 7) ^ sr8;
  const u16* Kg = qk + (tokBase + wave * 16 + sr8) * 2048 + 1024 + h * 64 + gch * 8;
  const u16* Vg = vt + ((long)bh * 64 + wave * 16 + sr8) * 2048 + gch * 8;
  u16* KL = &Kb[0][wave * 16 * 64] + lane * 8;
  u16* VL = &Vb[0][wave * 16 * 64] + lane * 8;

#define STAGE(S0, IB) do { \
    GLD16(Kg + (long)(S0) * 2048,          KL + (IB) * 4096); \
    GLD16(Kg + (long)((S0) + 8) * 2048,    KL + (IB) * 4096 + 512); \
    GLD16(Vg + (S0),                       VL + (IB) * 4096); \
    GLD16(Vg + (S0) + (long)8 * 2048,      VL + (IB) * 4096 + 512); \
  } while (0)

  STAGE(0, 0);

  // Q B-frags for 2 sub-tiles (rows q0 + wave*32 + t*16 + fm); pre-scaled
  bf16x8 qa[2][2];
#pragma unroll
  for (int t = 0; t < 2; t++) {
    const long qoff = (tokBase + q0 + wave * 32 + t * 16 + fm) * 2048 + h * 64;
    qa[t][0] = *(const bf16x8*)&qk[qoff + g * 8];
    qa[t][1] = *(const bf16x8*)&qk[qoff + 32 + g * 8];
  }

  f32x4 o[2][4] = {};
  f32x4 ol[2] = {};
  u16x8 onesu = {0x3F80, 0x3F80, 0x3F80, 0x3F80, 0x3F80, 0x3F80, 0x3F80, 0x3F80};
  bf16x8 ones = __builtin_bit_cast(bf16x8, onesu);

  int ib = 0;
  for (int s0 = 0; s0 < 2048; s0 += 64) {
    if (s0 + 64 < 2048) { STAGE(s0 + 64, ib ^ 1); WAITVM(4); }
    else                { WAITVM(0); }
    BARRIER();

    const u16* Kt = &Kb[ib][0];
    const u16* Vtile = &Vb[ib][0];

    // per 32-kv pair p (slices jj=2p, 2p+1): QK -> exp2/pack -> K=32 PV
#pragma unroll
    for (int p = 0; p < 2; p++) {
      u32x4 pk[2];  // [t]: 4 u32 = bf16x8 A-frag (k-slot 8g+i <- kv perm)
#pragma unroll
      for (int jh = 0; jh < 2; jh++) {
        const int jj = 2 * p + jh;
        bf16x8 k0 = *(const bf16x8*)&Kt[(jj * 16 + fm) * 64 + ((g    ) ^ f7) * 8];
        bf16x8 k1 = *(const bf16x8*)&Kt[(jj * 16 + fm) * 64 + ((4 + g) ^ f7) * 8];
#pragma unroll
        for (int t = 0; t < 2; t++) {
          f32x4 s = {};
          s = mfma16(k0, qa[t][0], s);
          s = mfma16(k1, qa[t][1], s);
          pk[t][2 * jh + 0] = cvtpk(__builtin_amdgcn_exp2f(s[0]), __builtin_amdgcn_exp2f(s[1]));
          pk[t][2 * jh + 1] = cvtpk(__builtin_amdgcn_exp2f(s[2]), __builtin_amdgcn_exp2f(s[3]));
        }
      }
      // V B-frags: single b128 per jd -- permuted chunk (4p+g), XOR-swizzled
      bf16x8 vb[4];
#pragma unroll
      for (int jd = 0; jd < 4; jd++)
        vb[jd] = *(const bf16x8*)&Vtile[(jd * 16 + fm) * 64 + ((4 * p + g) ^ f7) * 8];

      __builtin_amdgcn_s_setprio(1);
#pragma unroll
      for (int t = 0; t < 2; t++) {
        bf16x8 pa = __builtin_bit_cast(bf16x8, pk[t]);
#pragma unroll
        for (int jd = 0; jd < 4; jd++)
          o[t][jd] = mfma16(pa, vb[jd], o[t][jd]);
        ol[t] = mfma16(pa, ones, ol[t]);
      }
      __builtin_amdgcn_s_setprio(0);
    }
    BARRIER();  // LDS reads consumed; next STAGE may overwrite
    ib ^= 1;
  }
#undef STAGE

  // ctx[token][h*64+d] = O / l  (l already in the right lane: row 4g+r)
#pragma unroll
  for (int t = 0; t < 2; t++) {
#pragma unroll
    for (int r = 0; r < 4; r++) {
      float inv = 1.0f / ol[t][r];
      const long obase = (tokBase + q0 + wave * 32 + t * 16 + g * 4 + r) * 1024 + h * 64;
#pragma unroll
      for (int jd = 0; jd < 4; jd++)
        ctx[obase + jd * 16 + fm] = to_bf16(o[t][jd][r] * inv);
    }
  }
}

// ---------------- launch ------------------------------------------------------
extern "C" void kernel_launch(void* const* d_in, const int* in_sizes, int n_in,
                              void* d_out, int out_size, void* d_ws, size_t ws_size,
                              hipStream_t stream) {
  const float* x  = (const float*)d_in[0];
  const float* wq = (const float*)d_in[1];
  const float* wd = (const float*)d_in[2];
  float* out = (float*)d_out;
  char* ws = (char*)d_ws;
  // ws layout (48 MiB total)
  u16* xb   = (u16*)(ws);                          //  8 MiB  x bf16 [4096,1024]
  u16* wqb  = (u16*)(ws + 8388608);                //  6 MiB  w_qkv bf16 [3072,1024]
  u16* wdb  = (u16*)(ws + 14680064);               //  2 MiB  w_dense bf16 [1024,1024]
  u16* qkb  = (u16*)(ws + 16777216);               // 16 MiB  q|k bf16 [4096,2048]
  u16* vtb  = (u16*)(ws + 33554432);               //  8 MiB  Vt bf16 [32,64,2048] (kv quad-permuted)
  u16* ctxb = (u16*)(ws + 41943040);               //  8 MiB  ctx bf16 [4096,1024]

  const float sscale = 0.125f * 1.44269504f;       // 1/sqrt(64) * log2(e)

  cvt_all<<<8192, 256, 0, stream>>>(x, wq, wd, xb, wqb, wdb);
  gemm_qkv<<<dim3(24, 32), 256, 0, stream>>>(xb, wqb, qkb, vtb, 1024, sscale);
  attn_kernel<<<512, 256, 0, stream>>>(qkb, vtb, ctxb);
  gemm_bt_n64<<<dim3(16, 32), 256, 0, stream>>>(ctxb, wdb, out, 4096, 1024, 1024);
}